// Round 9
// baseline (152.360 us; speedup 1.0000x reference)
//
#include <hip/hip_runtime.h>
#include <cstddef>

#define B_     4096
#define L_     64
#define OUT_   64
#define KS_    8
#define KK_    4
#define LOUT_  57
#define C_     3648      // OUT_*LOUT_ = 57*64
#define HID_   33
#define TEMP_  34.0f
#define EPS_   1e-5f
#define NCH_   256       // b-chunks for stats (16 rows each)
#define SROWS_ 16        // rows per stats block
#define NBW_   16        // rows per write block
#define NTILE_ 960       // 64 o * 15 l-tiles (l0 = 0,4,...,56)

typedef float f32x4 __attribute__((ext_vector_type(4)));

// 4-byte-aligned float4 access (c0 = o*57+l0 is not 16B aligned).
struct __attribute__((packed, aligned(4))) f4u { f32x4 v; };
__device__ __forceinline__ void store4(float* p, f32x4 v) {
    reinterpret_cast<f4u*>(p)->v = v;
}
__device__ __forceinline__ f32x4 load4(const float* p) {
    return reinterpret_cast<const f4u*>(p)->v;
}

// gelu tanh-form: x * sigmoid(1.5957691*x*(1+0.044715x^2)); max abs err ~5e-4.
__device__ __forceinline__ float gelu_f(float x) {
    float e = exp2f(-2.3022083f * x * fmaf(0.044715f * x, x, 1.0f));
    return x * __builtin_amdgcn_rcpf(1.0f + e);
}

// Stage ROWS rows of x as float4 slots [ROWS][17]; slot16 = dup of slot15 so
// the tail tile's garbage lanes read defined finite values.
template<int ROWS>
__device__ __forceinline__ void stage_rows(
    const float* __restrict__ x, int b0, int tid, float4 (*xs)[17])
{
    for (int idx = tid; idx < ROWS * 17; idx += 256) {
        int r = idx / 17, t = idx - r * 17;
        const float4* xrow = (const float4*)(x + (size_t)(b0 + r) * L_);
        xs[r][t] = xrow[t < 16 ? t : 15];
    }
}

// ---------------- kernel 1: attention weights ----------------
__global__ __launch_bounds__(128) void attn_kernel(
    const float* __restrict__ x, const float* __restrict__ fc1_w,
    const float* __restrict__ fc2_w, const float* __restrict__ fc2_b,
    float* __restrict__ attn_out)
{
    __shared__ float fc1s[HID_][L_];
    __shared__ float fc2s[KK_][HID_];
    __shared__ float fc2bs[KK_];
    int tid = threadIdx.x;
    for (int i = tid; i < HID_ * L_; i += 128) fc1s[i / L_][i % L_] = fc1_w[i];
    for (int i = tid; i < KK_ * HID_; i += 128) fc2s[i / HID_][i % HID_] = fc2_w[i];
    if (tid < KK_) fc2bs[tid] = fc2_b[tid];
    __syncthreads();

    int b = blockIdx.x * 128 + tid;

    float xr[L_];
    const float4* xp = (const float4*)(x + (size_t)b * L_);
    #pragma unroll
    for (int i = 0; i < L_ / 4; ++i) {
        float4 v = xp[i];
        xr[4*i] = v.x; xr[4*i+1] = v.y; xr[4*i+2] = v.z; xr[4*i+3] = v.w;
    }
    float logit[KK_] = {0.f, 0.f, 0.f, 0.f};
    for (int h = 0; h < HID_; ++h) {
        const float4* fr = (const float4*)&fc1s[h][0];
        float acc = 0.f;
        #pragma unroll
        for (int i = 0; i < L_ / 4; ++i) {
            float4 wv = fr[i];
            acc = fmaf(xr[4*i],   wv.x, acc);
            acc = fmaf(xr[4*i+1], wv.y, acc);
            acc = fmaf(xr[4*i+2], wv.z, acc);
            acc = fmaf(xr[4*i+3], wv.w, acc);
        }
        float a = gelu_f(acc);
        #pragma unroll
        for (int k = 0; k < KK_; ++k) logit[k] = fmaf(a, fc2s[k][h], logit[k]);
    }
    float z[KK_];
    #pragma unroll
    for (int k = 0; k < KK_; ++k) z[k] = (logit[k] + fc2bs[k]) * (1.0f / TEMP_);
    float mx = fmaxf(fmaxf(z[0], z[1]), fmaxf(z[2], z[3]));
    float e[KK_]; float s = 0.f;
    #pragma unroll
    for (int k = 0; k < KK_; ++k) { e[k] = __expf(z[k] - mx); s += e[k]; }
    float inv = __builtin_amdgcn_rcpf(s);
    #pragma unroll
    for (int k = 0; k < KK_; ++k) attn_out[(size_t)b * KK_ + k] = e[k] * inv;
}

// ---------------- kernel 2: batch statistics (channel-quad threads) ----------------
__global__ __launch_bounds__(256) void stats_kernel(
    const float* __restrict__ x, const float* __restrict__ weight,
    const float* __restrict__ bias, const float* __restrict__ attn,
    float* __restrict__ P, int use_partial)
{
    int tid = threadIdx.x;
    int tile = blockIdx.x * 256 + tid;
    int chunk = blockIdx.y;
    bool act = tile < NTILE_;
    int o  = act ? tile / 15 : 0;
    int lt = act ? tile - o * 15 : 0;
    int l0 = lt * 4;
    int c0 = o * LOUT_ + l0;
    bool full = (lt != 14);

    float w[KK_][KS_];
    float bk[KK_];
    #pragma unroll
    for (int k = 0; k < KK_; ++k) {
        bk[k] = bias[k * OUT_ + o];
        #pragma unroll
        for (int t = 0; t < KS_; ++t) w[k][t] = weight[(k * OUT_ + o) * KS_ + t];
    }

    __shared__ float4 xs[SROWS_][17];
    __shared__ float4 at4[SROWS_];
    int b0 = chunk * SROWS_;
    stage_rows<SROWS_>(x, b0, tid, xs);
    if (tid < SROWS_) at4[tid] = *(const float4*)(attn + (size_t)(b0 + tid) * KK_);
    __syncthreads();

    f32x4 s1 = {0,0,0,0}, s2 = {0,0,0,0}, t1 = {0,0,0,0}, t2 = {0,0,0,0};
    if (act) {
        #pragma unroll 2
        for (int r = 0; r < SROWS_; ++r) {
            float4 X0 = xs[r][lt], X1 = xs[r][lt+1], X2 = xs[r][lt+2];
            float xw[12] = {X0.x,X0.y,X0.z,X0.w, X1.x,X1.y,X1.z,X1.w,
                            X2.x,X2.y,X2.z,X2.w};
            float4 atv = at4[r];
            float kv[4][KK_];
            #pragma unroll
            for (int e = 0; e < 4; ++e)
                #pragma unroll
                for (int k = 0; k < KK_; ++k) {
                    float a = bk[k];
                    #pragma unroll
                    for (int t = 0; t < KS_; ++t) a = fmaf(xw[e + t], w[k][t], a);
                    kv[e][k] = a;
                }
            f32x4 g4;
            #pragma unroll
            for (int e = 0; e < 4; ++e) {
                float ov = atv.x * kv[e][0];
                ov = fmaf(atv.y, kv[e][1], ov);
                ov = fmaf(atv.z, kv[e][2], ov);
                ov = fmaf(atv.w, kv[e][3], ov);
                g4[e] = gelu_f(ov);
            }
            s1 = s1 + g4;
            s2 = __builtin_elementwise_fma(g4, g4, s2);
            #pragma unroll
            for (int k = 0; k < KK_; ++k) {
                f32x4 gk;
                #pragma unroll
                for (int e = 0; e < 4; ++e) gk[e] = gelu_f(kv[e][k]);
                t1 = t1 + gk;
                t2 = __builtin_elementwise_fma(gk, gk, t2);
            }
        }
    }
    if (!act) return;
    if (use_partial) {
        size_t base = (size_t)chunk * 4 * C_ + c0;
        if (full) {
            store4(&P[base], s1);
            store4(&P[base + C_], s2);
            store4(&P[base + 2 * C_], t1);
            store4(&P[base + 3 * C_], t2);
        } else {
            P[base] = s1.x; P[base + C_] = s2.x;
            P[base + 2 * C_] = t1.x; P[base + 3 * C_] = t2.x;
        }
    } else {
        int ne = full ? 4 : 1;
        for (int e = 0; e < ne; ++e) {
            atomicAdd(&P[c0 + e], s1[e]);
            atomicAdd(&P[C_ + c0 + e], s2[e]);
            atomicAdd(&P[2 * C_ + c0 + e], t1[e]);
            atomicAdd(&P[3 * C_ + c0 + e], t2[e]);
        }
    }
}

// ---------------- kernel 3: reduce partials, fold into scale/shift ----------------
__global__ __launch_bounds__(256) void finalize_kernel(
    const float* __restrict__ P, const float* __restrict__ gamma,
    const float* __restrict__ beta, float* __restrict__ F, int use_partial)
{
    __shared__ float red[4][64];
    int t = threadIdx.x;
    int cl = t & 63;
    int s = t >> 6;
    int c = blockIdx.x * 64 + cl;    // C_ = 57*64, always in range
    float a = 0.f;
    if (use_partial) {
        for (int ch = 0; ch < NCH_; ++ch)
            a += P[((size_t)ch * 4 + s) * C_ + c];
    } else {
        a = P[(size_t)s * C_ + c];
    }
    red[s][cl] = a;
    __syncthreads();
    if (t < 64) {
        float a0 = red[0][cl], a1 = red[1][cl], a2 = red[2][cl], a3 = red[3][cl];
        float m  = a0 * (1.0f / B_);
        float v  = a1 * (1.0f / B_) - m * m;
        float rs = rsqrtf(v + EPS_);
        float m2 = a2 * (1.0f / (B_ * KK_));
        float v2 = a3 * (1.0f / (B_ * KK_)) - m2 * m2;
        float rs2 = rsqrtf(v2 + EPS_);
        float ga = gamma[c], be = beta[c];
        F[c]          = rs * ga;             // scaleA
        F[C_ + c]     = be - m * rs * ga;    // shiftA
        F[2 * C_ + c] = rs2 * ga;            // scaleK
        F[3 * C_ + c] = be - m2 * rs2 * ga;  // shiftK
    }
}

// ---------------- kernel 4: recompute + normalize + write (dwordx4 stores) ----------------
__global__ __launch_bounds__(256) void write_kernel(
    const float* __restrict__ x, const float* __restrict__ weight,
    const float* __restrict__ bias, const float* __restrict__ attn,
    const float* __restrict__ F,
    float* __restrict__ out0, float* __restrict__ kwout)
{
    int tid = threadIdx.x;
    int tile = blockIdx.x * 256 + tid;
    bool act = tile < NTILE_;
    int o  = act ? tile / 15 : 0;
    int lt = act ? tile - o * 15 : 0;
    int l0 = lt * 4;
    int c0 = o * LOUT_ + l0;
    bool full = (lt != 14);

    float w[KK_][KS_];
    float bk[KK_];
    #pragma unroll
    for (int k = 0; k < KK_; ++k) {
        bk[k] = bias[k * OUT_ + o];
        #pragma unroll
        for (int t = 0; t < KS_; ++t) w[k][t] = weight[(k * OUT_ + o) * KS_ + t];
    }
    f32x4 sA = {0,0,0,0}, hA = {0,0,0,0}, sK = {0,0,0,0}, hK = {0,0,0,0};
    if (act) {
        sA = load4(F + c0); hA = load4(F + C_ + c0);
        sK = load4(F + 2 * C_ + c0); hK = load4(F + 3 * C_ + c0);
    }

    __shared__ float4 xs[NBW_][17];
    __shared__ float4 at4[NBW_];
    int b0 = blockIdx.y * NBW_;
    stage_rows<NBW_>(x, b0, tid, xs);
    if (tid < NBW_) at4[tid] = *(const float4*)(attn + (size_t)(b0 + tid) * KK_);
    __syncthreads();

    if (!act) return;

    #pragma unroll 2
    for (int r = 0; r < NBW_; ++r) {
        float4 X0 = xs[r][lt], X1 = xs[r][lt+1], X2 = xs[r][lt+2];
        float xw[12] = {X0.x,X0.y,X0.z,X0.w, X1.x,X1.y,X1.z,X1.w,
                        X2.x,X2.y,X2.z,X2.w};
        float4 atv = at4[r];
        float kv[4][KK_];
        #pragma unroll
        for (int e = 0; e < 4; ++e)
            #pragma unroll
            for (int k = 0; k < KK_; ++k) {
                float a = bk[k];
                #pragma unroll
                for (int t = 0; t < KS_; ++t) a = fmaf(xw[e + t], w[k][t], a);
                kv[e][k] = a;
            }
        f32x4 oo;
        #pragma unroll
        for (int e = 0; e < 4; ++e) {
            float ov = atv.x * kv[e][0];
            ov = fmaf(atv.y, kv[e][1], ov);
            ov = fmaf(atv.z, kv[e][2], ov);
            ov = fmaf(atv.w, kv[e][3], ov);
            float g = gelu_f(ov);
            oo[e] = fmaf(g, sA[e], hA[e]);
        }
        f32x4 kwv[KK_];
        #pragma unroll
        for (int k = 0; k < KK_; ++k) {
            f32x4 gk;
            #pragma unroll
            for (int e = 0; e < 4; ++e) gk[e] = gelu_f(kv[e][k]);
            kwv[k] = __builtin_elementwise_fma(gk, sK, hK);
        }
        int b = b0 + r;
        float* po = out0 + (size_t)b * C_ + c0;
        float* pb = kwout + (size_t)b * KK_ * C_ + c0;
        if (full) {
            store4(po, oo);
            store4(pb, kwv[0]);
            store4(pb + C_, kwv[1]);
            store4(pb + 2 * C_, kwv[2]);
            store4(pb + 3 * C_, kwv[3]);
        } else {
            po[0] = oo.x;
            pb[0] = kwv[0].x;
            pb[C_] = kwv[1].x;
            pb[2 * C_] = kwv[2].x;
            pb[3 * C_] = kwv[3].x;
        }
    }
}

extern "C" void kernel_launch(void* const* d_in, const int* in_sizes, int n_in,
                              void* d_out, int out_size, void* d_ws, size_t ws_size,
                              hipStream_t stream) {
    const float* x      = (const float*)d_in[0];
    const float* fc1_w  = (const float*)d_in[1];
    const float* fc2_w  = (const float*)d_in[2];
    const float* fc2_b  = (const float*)d_in[3];
    const float* weight = (const float*)d_in[4];
    const float* bias   = (const float*)d_in[5];
    const float* gamma  = (const float*)d_in[6];
    const float* beta   = (const float*)d_in[7];

    float* out  = (float*)d_out;
    float* out0 = out;                          // B*C
    float* attn = out + (size_t)B_ * C_;        // B*K
    float* kwout = attn + (size_t)B_ * KK_;     // B*K*C

    // ws layout: P (NCH_*4*C_ partials) then F (4*C_); atomic fallback uses 4*C_ + F.
    size_t need = (size_t)(NCH_ * 4 + 4) * C_ * sizeof(float);
    int use_partial = ws_size >= need;
    float* P = (float*)d_ws;
    float* F = P + (use_partial ? (size_t)NCH_ * 4 * C_ : (size_t)4 * C_);
    if (!use_partial)
        hipMemsetAsync(P, 0, 4 * C_ * sizeof(float), stream);

    attn_kernel<<<B_ / 128, 128, 0, stream>>>(x, fc1_w, fc2_w, fc2_b, attn);
    stats_kernel<<<dim3(4, NCH_), 256, 0, stream>>>(
        x, weight, bias, attn, P, use_partial);
    finalize_kernel<<<C_ / 64, 256, 0, stream>>>(P, gamma, beta, F, use_partial);
    write_kernel<<<dim3(4, B_ / NBW_), 256, 0, stream>>>(
        x, weight, bias, attn, F, out0, kwout);
}